// Round 6
// baseline (412.009 us; speedup 1.0000x reference)
//
#include <hip/hip_runtime.h>
#include <hip/hip_cooperative_groups.h>

#define KC 32
#define CH 16
#define NB 8
#define NPI (512*512)
#define TPB 256               // 4 waves per block
#define NBLK 1024             // 4 blocks/CU -> 16 waves/CU
#define BPI (NBLK/NB)         // 128 blocks per image
#define PPB (NPI/BPI)         // 2048 px per block
#define SPW (PPB/4)           // 512 px per wave (phase A)
#define SCH (SPW/64)          // 8 chunks of 64 px

// ws layout (floats); every cell written before read each call -> no pre-zero
#define WS_PART 0                          // [1024][544] per-block segsum partials
#define WS_CEN (WS_PART + NBLK*544)        // [8][16][32] centroids [c][k]
#define WS_PR  (WS_CEN + NB*CH*KC)         // [8] push + 1e-4*reg
#define WS_PLP (WS_PR + NB)                // [1024] per-block pull partials

typedef float f32x16 __attribute__((ext_vector_type(16)));
typedef short short8 __attribute__((ext_vector_type(8)));

__device__ __forceinline__ unsigned short f2bf(float x) {
  unsigned u = __builtin_bit_cast(unsigned, x);
  u += 0x7FFFu + ((u >> 16) & 1u);          // RNE to bf16
  return (unsigned short)(u >> 16);
}
__device__ __forceinline__ unsigned packbf(float lo, float hi) {
  return (unsigned)f2bf(lo) | ((unsigned)f2bf(hi) << 16);
}

__device__ __forceinline__ void mfmaStep(f32x16& acc, unsigned (*sm)[68],
                                         int* sl, int h, int m) {
  #pragma unroll
  for (int s = 0; s < 4; ++s) {
    const int4* lp = (const int4*)&sl[s * 16 + 8 * h];
    const int4 la = lp[0], lb = lp[1];
    const short ONE = (short)0x3F80;  // bf16 1.0
    short8 av;
    av[0] = (la.x == m) ? ONE : (short)0; av[1] = (la.y == m) ? ONE : (short)0;
    av[2] = (la.z == m) ? ONE : (short)0; av[3] = (la.w == m) ? ONE : (short)0;
    av[4] = (lb.x == m) ? ONE : (short)0; av[5] = (lb.y == m) ? ONE : (short)0;
    av[6] = (lb.z == m) ? ONE : (short)0; av[7] = (lb.w == m) ? ONE : (short)0;
    short8 bv;
    if (m < CH) {
      const uint4* fp = (const uint4*)&sm[m >> 1][s * 16 + 8 * h];
      const uint4 u0 = fp[0], u1 = fp[1];
      const unsigned sh = (unsigned)(m & 1) * 16u;
      bv[0] = (short)((u0.x >> sh) & 0xFFFFu); bv[1] = (short)((u0.y >> sh) & 0xFFFFu);
      bv[2] = (short)((u0.z >> sh) & 0xFFFFu); bv[3] = (short)((u0.w >> sh) & 0xFFFFu);
      bv[4] = (short)((u1.x >> sh) & 0xFFFFu); bv[5] = (short)((u1.y >> sh) & 0xFFFFu);
      bv[6] = (short)((u1.z >> sh) & 0xFFFFu); bv[7] = (short)((u1.w >> sh) & 0xFFFFu);
    } else {
      const short cv = (m == CH) ? ONE : (short)0;   // col 16 = ones -> counts
      #pragma unroll
      for (int e = 0; e < 8; ++e) bv[e] = cv;
    }
    acc = __builtin_amdgcn_mfma_f32_32x32x16_bf16(av, bv, acc, 0, 0, 0);
  }
}

// -------- Phase A: segment-sum via onehot^T * emb (MFMA), 2-deep pipeline --------
__device__ __forceinline__ void phaseA(const float4* __restrict__ embv,
                                       const int* __restrict__ lab,
                                       float* __restrict__ ws, int bid, int t) {
  __shared__ unsigned smem[4][8][68];
  __shared__ int      slab[4][64];
  __shared__ float    sred[4][KC * 17];

  const int w = t >> 6, l = t & 63;
  const int h = l >> 5, m = l & 31;
  const int b = bid / BPI, blk = bid % BPI;
  const size_t base = (size_t)b * NPI + (size_t)blk * PPB + (size_t)w * SPW;

  f32x16 acc;
  #pragma unroll
  for (int i = 0; i < 16; ++i) acc[i] = 0.f;

  float4 a0, a1, a2, a3; int al;
  float4 b0, b1, b2, b3; int bl;
  {
    const float4* ep = embv + (base + l) * 4;
    a0 = ep[0]; a1 = ep[1]; a2 = ep[2]; a3 = ep[3];
    al = lab[base + l];
  }
  {
    const float4* ep = embv + (base + 64 + l) * 4;
    b0 = ep[0]; b1 = ep[1]; b2 = ep[2]; b3 = ep[3];
    bl = lab[base + 64 + l];
  }

  #pragma unroll
  for (int ch = 0; ch < SCH; ch += 2) {
    // stage set A, then refill A with chunk ch+2 (loads in flight over 2 MFMA steps)
    smem[w][0][l] = packbf(a0.x, a0.y); smem[w][1][l] = packbf(a0.z, a0.w);
    smem[w][2][l] = packbf(a1.x, a1.y); smem[w][3][l] = packbf(a1.z, a1.w);
    smem[w][4][l] = packbf(a2.x, a2.y); smem[w][5][l] = packbf(a2.z, a2.w);
    smem[w][6][l] = packbf(a3.x, a3.y); smem[w][7][l] = packbf(a3.z, a3.w);
    slab[w][l] = al;
    if (ch + 2 < SCH) {
      const size_t p = base + (size_t)(ch + 2) * 64 + l;
      const float4* ep = embv + p * 4;
      a0 = ep[0]; a1 = ep[1]; a2 = ep[2]; a3 = ep[3];
      al = lab[p];
    }
    mfmaStep(acc, smem[w], slab[w], h, m);

    // stage set B, refill B with chunk ch+3
    smem[w][0][l] = packbf(b0.x, b0.y); smem[w][1][l] = packbf(b0.z, b0.w);
    smem[w][2][l] = packbf(b1.x, b1.y); smem[w][3][l] = packbf(b1.z, b1.w);
    smem[w][4][l] = packbf(b2.x, b2.y); smem[w][5][l] = packbf(b2.z, b2.w);
    smem[w][6][l] = packbf(b3.x, b3.y); smem[w][7][l] = packbf(b3.z, b3.w);
    slab[w][l] = bl;
    if (ch + 3 < SCH) {
      const size_t p = base + (size_t)(ch + 3) * 64 + l;
      const float4* ep = embv + p * 4;
      b0 = ep[0]; b1 = ep[1]; b2 = ep[2]; b3 = ep[3];
      bl = lab[p];
    }
    mfmaStep(acc, smem[w], slab[w], h, m);
  }

  if (m < 17) {
    #pragma unroll
    for (int r = 0; r < 16; ++r) {
      const int row = (r & 3) + 8 * (r >> 2) + 4 * h;   // verified C/D layout
      sred[w][row * 17 + m] = acc[r];
    }
  }
  __syncthreads();
  for (int i = t; i < KC * 17; i += TPB) {
    const float v = sred[0][i] + sred[1][i] + sred[2][i] + sred[3][i];
    ws[WS_PART + (size_t)bid * 544 + i] = v;
  }
}

// -------- Phase B: centroids + push + reg (one block per image) --------
__device__ __forceinline__ void phaseB(float* __restrict__ ws, int bb, int t) {
  __shared__ float sums_s[KC * 17];
  __shared__ float cs[CH * KC];     // [c][k]
  __shared__ float validf[KC];
  __shared__ float redb[4];
  const int w = t >> 6, l = t & 63;

  for (int i = t; i < KC * 17; i += TPB) {
    float s = 0.f;
    const float* p0 = ws + WS_PART + (size_t)(bb * BPI) * 544 + i;
    for (int p = 0; p < BPI; ++p) s += p0[(size_t)p * 544];
    sums_s[i] = s;
  }
  __syncthreads();
  if (t < KC) validf[t] = (sums_s[t * 17 + 16] > 0.f) ? 1.f : 0.f;

  float regacc = 0.f;
  for (int idx = t; idx < KC * CH; idx += TPB) {
    const int k = idx & 31, c = idx >> 5;
    const float cnt = sums_s[k * 17 + 16];
    const float ce  = (cnt > 0.f) ? sums_s[k * 17 + c] / cnt : 0.f;
    cs[c * KC + k] = ce;
    ws[WS_CEN + (size_t)bb * CH * KC + c * KC + k] = ce;
    regacc += ce * ce;
  }
  __syncthreads();

  float pushacc = 0.f;
  for (int p = t; p < KC * KC; p += TPB) {
    const int i = p >> 5, j = p & 31;
    if (i < j && validf[i] > 0.f && validf[j] > 0.f) {
      float pd = 0.f;
      #pragma unroll
      for (int cc = 0; cc < CH; ++cc)
        pd += fabsf(cs[cc * KC + i] - cs[cc * KC + j]);
      const float hi = 0.25f - pd;
      if (hi > 0.f) pushacc += hi * hi;
    }
  }

  float v = pushacc;
  #pragma unroll
  for (int off = 32; off; off >>= 1) v += __shfl_down(v, off, 64);
  if (l == 0) redb[w] = v;
  __syncthreads();
  float pushsum = 0.f;
  if (t == 0) { for (int i = 0; i < 4; ++i) pushsum += redb[i]; }
  __syncthreads();

  v = regacc;
  #pragma unroll
  for (int off = 32; off; off >>= 1) v += __shfl_down(v, off, 64);
  if (l == 0) redb[w] = v;
  __syncthreads();

  if (t == 0) {
    float regsum = 0.f;
    for (int i = 0; i < 4; ++i) regsum += redb[i];
    float nv = 0.f;
    for (int i = 0; i < KC; ++i) nv += validf[i];
    const float ncomp = nv * (nv - 1.f) * 0.5f;
    const float push  = (nv >= 2.f) ? pushsum / fmaxf(ncomp, 1.f) : 0.f;
    const float reg   = regsum / fmaxf(nv * (float)CH, 1.f);
    ws[WS_PR + bb] = push + 1e-4f * reg;
  }
}

// -------- Phase C: pull loss, second streaming pass (fp32 exact, L3-served) --------
__device__ __forceinline__ float pullPx(const float* __restrict__ prow,
                                        float4 e0, float4 e1, float4 e2, float4 e3) {
  const float4* pr = (const float4*)prow;
  const float4 q0 = pr[0], q1 = pr[1], q2 = pr[2], q3 = pr[3];
  float d = 0.f;
  d += fabsf(e0.x - q0.x); d += fabsf(e0.y - q0.y);
  d += fabsf(e0.z - q0.z); d += fabsf(e0.w - q0.w);
  d += fabsf(e1.x - q1.x); d += fabsf(e1.y - q1.y);
  d += fabsf(e1.z - q1.z); d += fabsf(e1.w - q1.w);
  d += fabsf(e2.x - q2.x); d += fabsf(e2.y - q2.y);
  d += fabsf(e2.z - q2.z); d += fabsf(e2.w - q2.w);
  d += fabsf(e3.x - q3.x); d += fabsf(e3.y - q3.y);
  d += fabsf(e3.z - q3.z); d += fabsf(e3.w - q3.w);
  return d;
}

__device__ __forceinline__ void phaseC(const float4* __restrict__ embv,
                                       const int* __restrict__ lab,
                                       float* __restrict__ ws, int bid, int t) {
  __shared__ float pcent[KC * 20];  // [k][c], stride 20 -> 16B-aligned rows for b128
  __shared__ float redc[4];
  const int w = t >> 6, l = t & 63;
  const int b = bid / BPI, blk = bid % BPI;
  for (int i = t; i < CH * KC; i += TPB) {
    const int k = i & 31, c = i >> 5;
    pcent[k * 20 + c] = ws[WS_CEN + (size_t)b * CH * KC + c * KC + k];
  }
  __syncthreads();

  const size_t base = (size_t)b * NPI + (size_t)blk * PPB;
  float pacc = 0.f;

  int la, lb_;
  float4 fa0, fa1, fa2, fa3, fb0, fb1, fb2, fb3;
  {
    const size_t p = base + t;
    const float4* ep = embv + p * 4;
    fa0 = ep[0]; fa1 = ep[1]; fa2 = ep[2]; fa3 = ep[3];
    la = lab[p];
  }
  {
    const size_t p = base + 256 + t;
    const float4* ep = embv + p * 4;
    fb0 = ep[0]; fb1 = ep[1]; fb2 = ep[2]; fb3 = ep[3];
    lb_ = lab[p];
  }

  #pragma unroll
  for (int q = 0; q < 8; q += 2) {
    {
      const float d = pullPx(&pcent[la * 20], fa0, fa1, fa2, fa3);
      pacc += d * d;
    }
    if (q + 2 < 8) {
      const size_t p = base + (size_t)(q + 2) * 256 + t;
      const float4* ep = embv + p * 4;
      fa0 = ep[0]; fa1 = ep[1]; fa2 = ep[2]; fa3 = ep[3];
      la = lab[p];
    }
    {
      const float d = pullPx(&pcent[lb_ * 20], fb0, fb1, fb2, fb3);
      pacc += d * d;
    }
    if (q + 3 < 8) {
      const size_t p = base + (size_t)(q + 3) * 256 + t;
      const float4* ep = embv + p * 4;
      fb0 = ep[0]; fb1 = ep[1]; fb2 = ep[2]; fb3 = ep[3];
      lb_ = lab[p];
    }
  }

  float v = pacc;
  #pragma unroll
  for (int off = 32; off; off >>= 1) v += __shfl_down(v, off, 64);
  if (l == 0) redc[w] = v;
  __syncthreads();
  if (t == 0) ws[WS_PLP + bid] = redc[0] + redc[1] + redc[2] + redc[3];
}

// -------- Phase D: final reduce --------
__device__ __forceinline__ void phaseD(const float* __restrict__ ws,
                                       float* __restrict__ out, int t) {
  __shared__ float simg[NB];
  const int img = t >> 5, j = t & 31;   // 32 threads per image, 8 images = 256
  float v = 0.f;
  #pragma unroll
  for (int q = 0; q < BPI / 32; ++q)
    v += ws[WS_PLP + img * BPI + j + 32 * q];
  #pragma unroll
  for (int off = 16; off; off >>= 1) v += __shfl_down(v, off, 32);
  if (j == 0) simg[img] = v;
  __syncthreads();
  if (t == 0) {
    float s = 0.f;
    for (int bb = 0; bb < NB; ++bb)
      s += ws[WS_PR + bb] + simg[bb] * (1.f / (float)NPI);
    out[0] = s * (1.f / (float)NB);
  }
}

__global__ __launch_bounds__(TPB, 4) void fused_kernel(
    const float4* __restrict__ embv, const int* __restrict__ lab,
    float* __restrict__ ws, float* __restrict__ out) {
  cooperative_groups::grid_group grid = cooperative_groups::this_grid();
  phaseA(embv, lab, ws, blockIdx.x, threadIdx.x);
  grid.sync();
  if (blockIdx.x < NB) phaseB(ws, blockIdx.x, threadIdx.x);
  grid.sync();
  phaseC(embv, lab, ws, blockIdx.x, threadIdx.x);
  grid.sync();
  if (blockIdx.x == 0) phaseD(ws, out, threadIdx.x);
}

// -------- Fallback: same phases as 4 plain kernels (if coop launch is rejected) --------
__global__ __launch_bounds__(TPB) void kA(const float4* __restrict__ e,
                                          const int* __restrict__ la,
                                          float* __restrict__ ws) {
  phaseA(e, la, ws, blockIdx.x, threadIdx.x);
}
__global__ __launch_bounds__(TPB) void kB(float* __restrict__ ws) {
  phaseB(ws, blockIdx.x, threadIdx.x);
}
__global__ __launch_bounds__(TPB) void kC(const float4* __restrict__ e,
                                          const int* __restrict__ la,
                                          float* __restrict__ ws) {
  phaseC(e, la, ws, blockIdx.x, threadIdx.x);
}
__global__ __launch_bounds__(TPB) void kD(const float* __restrict__ ws,
                                          float* __restrict__ out) {
  phaseD(ws, out, threadIdx.x);
}

extern "C" void kernel_launch(void* const* d_in, const int* in_sizes, int n_in,
                              void* d_out, int out_size, void* d_ws, size_t ws_size,
                              hipStream_t stream) {
  const float4* emb = (const float4*)d_in[0];
  const int*    labp = (const int*)d_in[1];
  float* wsp  = (float*)d_ws;
  float* outp = (float*)d_out;
  void* args[] = {(void*)&emb, (void*)&labp, (void*)&wsp, (void*)&outp};
  hipError_t err = hipLaunchCooperativeKernel((const void*)fused_kernel,
                                              dim3(NBLK), dim3(TPB), args, 0, stream);
  if (err != hipSuccess) {
    (void)hipGetLastError();   // clear sticky error, use plain-kernel path
    hipLaunchKernelGGL(kA, dim3(NBLK), dim3(TPB), 0, stream, emb, labp, wsp);
    hipLaunchKernelGGL(kB, dim3(NB), dim3(TPB), 0, stream, wsp);
    hipLaunchKernelGGL(kC, dim3(NBLK), dim3(TPB), 0, stream, emb, labp, wsp);
    hipLaunchKernelGGL(kD, dim3(1), dim3(TPB), 0, stream, wsp, outp);
  }
}

// Round 7
// 104.947 us; speedup vs baseline: 3.9259x; 3.9259x over previous
//
#include <hip/hip_runtime.h>

#define KC 32
#define CH 16
#define NB 8
#define NPI (512*512)

// segsum decomposition: 2048 blocks of 256 threads (8 blocks/CU)
#define SBPI 256              // blocks per image
#define SPPB (NPI/SBPI)       // 1024 px per block
#define SPW  (SPPB/4)         // 256 px per wave
#define SCH  (SPW/64)         // 4 chunks of 64 px

// pull decomposition: 2048 blocks of 256 threads
#define PBPI 256
#define PPPB (NPI/PBPI)       // 1024
#define PIT  (PPPB/256)       // 4

// ws layout (floats)
#define WS_CNT 0                         // [8][32]
#define WS_SUM (WS_CNT + NB*KC)          // [8][32][16]
#define WS_CEN (WS_SUM + NB*KC*CH)       // [8][16][32]
#define WS_PR  (WS_CEN + NB*CH*KC)       // [8]
#define WS_PLP (WS_PR + NB)              // [8*PBPI] pull partials (overwritten each call)
#define WS_NZERO (NB*KC + NB*KC*CH)      // only CNT+SUM are atomically accumulated

typedef float f32x16 __attribute__((ext_vector_type(16)));
typedef short short8 __attribute__((ext_vector_type(8)));

__device__ __forceinline__ unsigned short f2bf(float x) {
  unsigned u = __builtin_bit_cast(unsigned, x);
  u += 0x7FFFu + ((u >> 16) & 1u);          // RNE to bf16
  return (unsigned short)(u >> 16);
}
__device__ __forceinline__ unsigned packbf(float lo, float hi) {
  return (unsigned)f2bf(lo) | ((unsigned)f2bf(hi) << 16);
}

__global__ void zero_ws_kernel(float* __restrict__ ws) {
  int i = blockIdx.x * 256 + threadIdx.x;
  if (i < WS_NZERO) ws[i] = 0.f;
}

// sums[k][c] + counts[k] via onehot^T * emb, one 32x32x16 bf16 MFMA per 16 pixels.
// Per-wave private LDS staging (in-order DS per wave => no barriers in hot loop).
__global__ __launch_bounds__(256) void segsum_kernel(
    const float4* __restrict__ embv, const int* __restrict__ lab,
    float* __restrict__ ws) {
  __shared__ unsigned smem[4][8][68];   // [wave][ch-pair][px + pad] bf16x2
  __shared__ int      slab[4][64];
  __shared__ float    sred[4][KC * 17];

  const int t = threadIdx.x, w = t >> 6, l = t & 63;
  const int b = blockIdx.x / SBPI, blk = blockIdx.x % SBPI;
  const size_t base = (size_t)b * NPI + (size_t)blk * SPPB + (size_t)w * SPW;
  const int h = l >> 5;     // k-half of the MFMA operands
  const int m = l & 31;     // A row (label) / B col (channel|count)

  f32x16 acc;
  #pragma unroll
  for (int i = 0; i < 16; ++i) acc[i] = 0.f;

  float4 c0, c1, c2, c3; int cl;
  {
    const float4* ep = embv + (base + l) * 4;
    c0 = ep[0]; c1 = ep[1]; c2 = ep[2]; c3 = ep[3];
    cl = lab[base + l];
  }

  for (int ch = 0; ch < SCH; ++ch) {
    smem[w][0][l] = packbf(c0.x, c0.y);
    smem[w][1][l] = packbf(c0.z, c0.w);
    smem[w][2][l] = packbf(c1.x, c1.y);
    smem[w][3][l] = packbf(c1.z, c1.w);
    smem[w][4][l] = packbf(c2.x, c2.y);
    smem[w][5][l] = packbf(c2.z, c2.w);
    smem[w][6][l] = packbf(c3.x, c3.y);
    smem[w][7][l] = packbf(c3.z, c3.w);
    slab[w][l] = cl;

    if (ch + 1 < SCH) {                 // prefetch next chunk under the MFMA steps
      const size_t p = base + (size_t)(ch + 1) * 64 + l;
      const float4* ep = embv + p * 4;
      c0 = ep[0]; c1 = ep[1]; c2 = ep[2]; c3 = ep[3];
      cl = lab[p];
    }

    #pragma unroll
    for (int s = 0; s < 4; ++s) {
      const int4* lp = (const int4*)&slab[w][s * 16 + 8 * h];
      const int4 la = lp[0], lb = lp[1];
      const short ONE = (short)0x3F80;  // bf16 1.0
      short8 av;
      av[0] = (la.x == m) ? ONE : (short)0; av[1] = (la.y == m) ? ONE : (short)0;
      av[2] = (la.z == m) ? ONE : (short)0; av[3] = (la.w == m) ? ONE : (short)0;
      av[4] = (lb.x == m) ? ONE : (short)0; av[5] = (lb.y == m) ? ONE : (short)0;
      av[6] = (lb.z == m) ? ONE : (short)0; av[7] = (lb.w == m) ? ONE : (short)0;

      short8 bv;
      if (m < CH) {
        const uint4* fp = (const uint4*)&smem[w][m >> 1][s * 16 + 8 * h];
        const uint4 u0 = fp[0], u1 = fp[1];
        const unsigned sh = (unsigned)(m & 1) * 16u;
        bv[0] = (short)((u0.x >> sh) & 0xFFFFu); bv[1] = (short)((u0.y >> sh) & 0xFFFFu);
        bv[2] = (short)((u0.z >> sh) & 0xFFFFu); bv[3] = (short)((u0.w >> sh) & 0xFFFFu);
        bv[4] = (short)((u1.x >> sh) & 0xFFFFu); bv[5] = (short)((u1.y >> sh) & 0xFFFFu);
        bv[6] = (short)((u1.z >> sh) & 0xFFFFu); bv[7] = (short)((u1.w >> sh) & 0xFFFFu);
      } else {
        const short cv = (m == CH) ? ONE : (short)0;   // col 16 = ones -> counts
        #pragma unroll
        for (int e = 0; e < 8; ++e) bv[e] = cv;
      }
      acc = __builtin_amdgcn_mfma_f32_32x32x16_bf16(av, bv, acc, 0, 0, 0);
    }
  }

  // block-level reduce of the 4 waves' [32 x 17] partials, then one atomic per cell
  if (m < 17) {
    #pragma unroll
    for (int r = 0; r < 16; ++r) {
      const int row = (r & 3) + 8 * (r >> 2) + 4 * h;   // verified C/D layout (m74/m101)
      sred[w][row * 17 + m] = acc[r];
    }
  }
  __syncthreads();
  for (int i = t; i < KC * 17; i += 256) {
    const float v = sred[0][i] + sred[1][i] + sred[2][i] + sred[3][i];
    const int row = i / 17, c = i - row * 17;
    float* dst = (c < CH) ? &ws[WS_SUM + (b * KC + row) * CH + c]
                          : &ws[WS_CNT + b * KC + row];
    __hip_atomic_fetch_add(dst, v, __ATOMIC_RELAXED, __HIP_MEMORY_SCOPE_AGENT);
  }
}

__global__ __launch_bounds__(512) void centroid_push_kernel(float* __restrict__ ws) {
  __shared__ float cent[CH * KC];   // [c][k]
  __shared__ float validf[KC];
  __shared__ float red[8];
  const int b = blockIdx.x, t = threadIdx.x;
  const float* gcnt = ws + WS_CNT + b * KC;
  const float* gsum = ws + WS_SUM + (size_t)b * KC * CH;

  if (t < KC) validf[t] = (gcnt[t] > 0.f) ? 1.f : 0.f;

  const int k = t & 31, c = t >> 5;
  const float cnt = gcnt[k];
  const float ce  = (cnt > 0.f) ? gsum[k * CH + c] / cnt : 0.f;
  cent[c * KC + k] = ce;
  ws[WS_CEN + (size_t)b * CH * KC + c * KC + k] = ce;
  const float regacc = ce * ce;
  __syncthreads();

  float pushacc = 0.f;
  for (int p = t; p < KC * KC; p += 512) {
    const int i = p >> 5, j = p & 31;
    if (i < j && validf[i] > 0.f && validf[j] > 0.f) {
      float pd = 0.f;
      #pragma unroll
      for (int cc = 0; cc < CH; ++cc)
        pd += fabsf(cent[cc * KC + i] - cent[cc * KC + j]);
      const float hi = 0.25f - pd;
      if (hi > 0.f) pushacc += hi * hi;
    }
  }

  float v = pushacc;
  #pragma unroll
  for (int off = 32; off; off >>= 1) v += __shfl_down(v, off, 64);
  if ((t & 63) == 0) red[t >> 6] = v;
  __syncthreads();
  float pushsum = 0.f;
  if (t == 0) { for (int i = 0; i < 8; ++i) pushsum += red[i]; }
  __syncthreads();

  v = regacc;
  #pragma unroll
  for (int off = 32; off; off >>= 1) v += __shfl_down(v, off, 64);
  if ((t & 63) == 0) red[t >> 6] = v;
  __syncthreads();

  if (t == 0) {
    float regsum = 0.f;
    for (int i = 0; i < 8; ++i) regsum += red[i];
    float nv = 0.f;
    for (int i = 0; i < KC; ++i) nv += validf[i];
    const float ncomp = nv * (nv - 1.f) * 0.5f;
    const float push  = (nv >= 2.f) ? pushsum / fmaxf(ncomp, 1.f) : 0.f;
    const float reg   = regsum / fmaxf(nv * (float)CH, 1.f);
    ws[WS_PR + b] = push + 1e-4f * reg;
  }
}

__global__ __launch_bounds__(256) void pull_kernel(
    const float4* __restrict__ embv, const int* __restrict__ lab,
    float* __restrict__ ws) {
  __shared__ float cent[CH * KC];   // [c][k]: read bank == label -> broadcast/spread, conflict-free
  __shared__ float red[4];
  const int t = threadIdx.x;
  const int b = blockIdx.x / PBPI, blk = blockIdx.x % PBPI;
  for (int i = t; i < CH * KC; i += 256)
    cent[i] = ws[WS_CEN + (size_t)b * CH * KC + i];
  __syncthreads();

  float acc = 0.f;
  const size_t pix0 = (size_t)b * NPI + (size_t)blk * PPPB;
  for (int it = 0; it < PIT; ++it) {
    const size_t p = pix0 + (size_t)it * 256 + t;
    const int L = lab[p];
    const float4 v0 = embv[p * 4 + 0];
    const float4 v1 = embv[p * 4 + 1];
    const float4 v2 = embv[p * 4 + 2];
    const float4 v3 = embv[p * 4 + 3];
    float d = 0.f;
    d += fabsf(v0.x - cent[ 0 * KC + L]);
    d += fabsf(v0.y - cent[ 1 * KC + L]);
    d += fabsf(v0.z - cent[ 2 * KC + L]);
    d += fabsf(v0.w - cent[ 3 * KC + L]);
    d += fabsf(v1.x - cent[ 4 * KC + L]);
    d += fabsf(v1.y - cent[ 5 * KC + L]);
    d += fabsf(v1.z - cent[ 6 * KC + L]);
    d += fabsf(v1.w - cent[ 7 * KC + L]);
    d += fabsf(v2.x - cent[ 8 * KC + L]);
    d += fabsf(v2.y - cent[ 9 * KC + L]);
    d += fabsf(v2.z - cent[10 * KC + L]);
    d += fabsf(v2.w - cent[11 * KC + L]);
    d += fabsf(v3.x - cent[12 * KC + L]);
    d += fabsf(v3.y - cent[13 * KC + L]);
    d += fabsf(v3.z - cent[14 * KC + L]);
    d += fabsf(v3.w - cent[15 * KC + L]);
    acc += d * d;
  }
  #pragma unroll
  for (int off = 32; off; off >>= 1) acc += __shfl_down(acc, off, 64);
  if ((t & 63) == 0) red[t >> 6] = acc;
  __syncthreads();
  if (t == 0) ws[WS_PLP + blockIdx.x] = red[0] + red[1] + red[2] + red[3];
}

__global__ void final_kernel(const float* __restrict__ ws, float* __restrict__ out) {
  __shared__ float simg[NB];
  const int t = threadIdx.x;            // 256 threads
  const int img = t >> 5, j = t & 31;   // 32 threads per image
  float v = 0.f;
  #pragma unroll
  for (int q = 0; q < PBPI / 32; ++q)
    v += ws[WS_PLP + img * PBPI + j + 32 * q];
  #pragma unroll
  for (int off = 16; off; off >>= 1) v += __shfl_down(v, off, 32);
  if (j == 0) simg[img] = v;
  __syncthreads();
  if (t == 0) {
    float s = 0.f;
    for (int b2 = 0; b2 < NB; ++b2)
      s += ws[WS_PR + b2] + simg[b2] * (1.f / (float)NPI);
    out[0] = s * (1.f / (float)NB);
  }
}

extern "C" void kernel_launch(void* const* d_in, const int* in_sizes, int n_in,
                              void* d_out, int out_size, void* d_ws, size_t ws_size,
                              hipStream_t stream) {
  const float4* emb = (const float4*)d_in[0];
  const int*    lab = (const int*)d_in[1];
  float* ws  = (float*)d_ws;
  float* out = (float*)d_out;

  hipLaunchKernelGGL(zero_ws_kernel, dim3((WS_NZERO + 255) / 256), dim3(256), 0, stream, ws);
  hipLaunchKernelGGL(segsum_kernel, dim3(NB * SBPI), dim3(256), 0, stream, emb, lab, ws);
  hipLaunchKernelGGL(centroid_push_kernel, dim3(NB), dim3(512), 0, stream, ws);
  hipLaunchKernelGGL(pull_kernel, dim3(NB * PBPI), dim3(256), 0, stream, emb, lab, ws);
  hipLaunchKernelGGL(final_kernel, dim3(1), dim3(256), 0, stream, ws, out);
}

// Round 8
// 93.122 us; speedup vs baseline: 4.4244x; 1.1270x over previous
//
#include <hip/hip_runtime.h>

#define KC 32
#define CH 16
#define NB 8
#define NPI (512*512)

// segsum decomposition: 2048 blocks of 256 threads (8 blocks/CU)
#define SBPI 256              // blocks per image
#define SPPB (NPI/SBPI)       // 1024 px per block
#define SPW  (SPPB/4)         // 256 px per wave
#define SCH  (SPW/64)         // 4 chunks of 64 px

// pull decomposition: 2048 blocks of 256 threads
#define PBPI 256
#define PPPB (NPI/PBPI)       // 1024
#define PIT  (PPPB/256)       // 4

// ws layout (floats); every cell written before read each call -> no pre-zero
#define WS_PART 0                          // [2048][544] per-block segsum partials ([k][c|cnt])
#define WS_CEN (WS_PART + NB*SBPI*544)     // [8][16][32] centroids [c][k]
#define WS_PR  (WS_CEN + NB*CH*KC)         // [8] push + 1e-4*reg
#define WS_PLP (WS_PR + NB)                // [2048] pull partials

typedef float f32x16 __attribute__((ext_vector_type(16)));
typedef short short8 __attribute__((ext_vector_type(8)));

__device__ __forceinline__ unsigned short f2bf(float x) {
  unsigned u = __builtin_bit_cast(unsigned, x);
  u += 0x7FFFu + ((u >> 16) & 1u);          // RNE to bf16
  return (unsigned short)(u >> 16);
}
__device__ __forceinline__ unsigned packbf(float lo, float hi) {
  return (unsigned)f2bf(lo) | ((unsigned)f2bf(hi) << 16);
}

// sums[k][c] + counts[k] via onehot^T * emb, one 32x32x16 bf16 MFMA per 16 pixels.
// Per-wave private LDS staging (in-order DS per wave => no barriers in hot loop).
// Block partials stored with PLAIN stores (no atomics anywhere).
__global__ __launch_bounds__(256) void segsum_kernel(
    const float4* __restrict__ embv, const int* __restrict__ lab,
    float* __restrict__ ws) {
  __shared__ unsigned smem[4][8][68];   // [wave][ch-pair][px + pad] bf16x2
  __shared__ int      slab[4][64];
  __shared__ float    sred[4][KC * 17];

  const int t = threadIdx.x, w = t >> 6, l = t & 63;
  const int b = blockIdx.x / SBPI, blk = blockIdx.x % SBPI;
  const size_t base = (size_t)b * NPI + (size_t)blk * SPPB + (size_t)w * SPW;
  const int h = l >> 5;     // k-half of the MFMA operands
  const int m = l & 31;     // A row (label) / B col (channel|count)

  f32x16 acc;
  #pragma unroll
  for (int i = 0; i < 16; ++i) acc[i] = 0.f;

  float4 c0, c1, c2, c3; int cl;
  {
    const float4* ep = embv + (base + l) * 4;
    c0 = ep[0]; c1 = ep[1]; c2 = ep[2]; c3 = ep[3];
    cl = lab[base + l];
  }

  for (int ch = 0; ch < SCH; ++ch) {
    smem[w][0][l] = packbf(c0.x, c0.y);
    smem[w][1][l] = packbf(c0.z, c0.w);
    smem[w][2][l] = packbf(c1.x, c1.y);
    smem[w][3][l] = packbf(c1.z, c1.w);
    smem[w][4][l] = packbf(c2.x, c2.y);
    smem[w][5][l] = packbf(c2.z, c2.w);
    smem[w][6][l] = packbf(c3.x, c3.y);
    smem[w][7][l] = packbf(c3.z, c3.w);
    slab[w][l] = cl;

    if (ch + 1 < SCH) {                 // prefetch next chunk under the MFMA steps
      const size_t p = base + (size_t)(ch + 1) * 64 + l;
      const float4* ep = embv + p * 4;
      c0 = ep[0]; c1 = ep[1]; c2 = ep[2]; c3 = ep[3];
      cl = lab[p];
    }

    #pragma unroll
    for (int s = 0; s < 4; ++s) {
      const int4* lp = (const int4*)&slab[w][s * 16 + 8 * h];
      const int4 la = lp[0], lb = lp[1];
      const short ONE = (short)0x3F80;  // bf16 1.0
      short8 av;
      av[0] = (la.x == m) ? ONE : (short)0; av[1] = (la.y == m) ? ONE : (short)0;
      av[2] = (la.z == m) ? ONE : (short)0; av[3] = (la.w == m) ? ONE : (short)0;
      av[4] = (lb.x == m) ? ONE : (short)0; av[5] = (lb.y == m) ? ONE : (short)0;
      av[6] = (lb.z == m) ? ONE : (short)0; av[7] = (lb.w == m) ? ONE : (short)0;

      short8 bv;
      if (m < CH) {
        const uint4* fp = (const uint4*)&smem[w][m >> 1][s * 16 + 8 * h];
        const uint4 u0 = fp[0], u1 = fp[1];
        const unsigned sh = (unsigned)(m & 1) * 16u;
        bv[0] = (short)((u0.x >> sh) & 0xFFFFu); bv[1] = (short)((u0.y >> sh) & 0xFFFFu);
        bv[2] = (short)((u0.z >> sh) & 0xFFFFu); bv[3] = (short)((u0.w >> sh) & 0xFFFFu);
        bv[4] = (short)((u1.x >> sh) & 0xFFFFu); bv[5] = (short)((u1.y >> sh) & 0xFFFFu);
        bv[6] = (short)((u1.z >> sh) & 0xFFFFu); bv[7] = (short)((u1.w >> sh) & 0xFFFFu);
      } else {
        const short cv = (m == CH) ? ONE : (short)0;   // col 16 = ones -> counts
        #pragma unroll
        for (int e = 0; e < 8; ++e) bv[e] = cv;
      }
      acc = __builtin_amdgcn_mfma_f32_32x32x16_bf16(av, bv, acc, 0, 0, 0);
    }
  }

  // block-level reduce of the 4 waves' [32 x 17] partials, plain store of partials
  if (m < 17) {
    #pragma unroll
    for (int r = 0; r < 16; ++r) {
      const int row = (r & 3) + 8 * (r >> 2) + 4 * h;   // verified C/D layout (m74/m101)
      sred[w][row * 17 + m] = acc[r];
    }
  }
  __syncthreads();
  for (int i = t; i < KC * 17; i += 256) {
    const float v = sred[0][i] + sred[1][i] + sred[2][i] + sred[3][i];
    ws[WS_PART + (size_t)blockIdx.x * 544 + i] = v;
  }
}

// Reduce 256 block-partials per image, then centroids + push + reg. One block per image.
__global__ __launch_bounds__(512) void centroid_push_kernel(float* __restrict__ ws) {
  __shared__ float sums_s[KC * 17];  // [k][c|cnt]
  __shared__ float cent[CH * KC];    // [c][k]
  __shared__ float validf[KC];
  __shared__ float red[8];
  const int b = blockIdx.x, t = threadIdx.x;

  // coalesced partial reduce: thread i sums cell i over the image's 256 blocks
  for (int i = t; i < KC * 17; i += 512) {
    float s = 0.f;
    const float* p0 = ws + WS_PART + (size_t)(b * SBPI) * 544 + i;
    #pragma unroll 4
    for (int p = 0; p < SBPI; ++p) s += p0[(size_t)p * 544];
    sums_s[i] = s;
  }
  __syncthreads();

  if (t < KC) validf[t] = (sums_s[t * 17 + 16] > 0.f) ? 1.f : 0.f;

  const int k = t & 31, c = t >> 5;   // t in [0,512) covers all (k,c)
  const float cnt = sums_s[k * 17 + 16];
  const float ce  = (cnt > 0.f) ? sums_s[k * 17 + c] / cnt : 0.f;
  cent[c * KC + k] = ce;
  ws[WS_CEN + (size_t)b * CH * KC + c * KC + k] = ce;
  const float regacc = ce * ce;
  __syncthreads();

  float pushacc = 0.f;
  for (int p = t; p < KC * KC; p += 512) {
    const int i = p >> 5, j = p & 31;
    if (i < j && validf[i] > 0.f && validf[j] > 0.f) {
      float pd = 0.f;
      #pragma unroll
      for (int cc = 0; cc < CH; ++cc)
        pd += fabsf(cent[cc * KC + i] - cent[cc * KC + j]);
      const float hi = 0.25f - pd;
      if (hi > 0.f) pushacc += hi * hi;
    }
  }

  float v = pushacc;
  #pragma unroll
  for (int off = 32; off; off >>= 1) v += __shfl_down(v, off, 64);
  if ((t & 63) == 0) red[t >> 6] = v;
  __syncthreads();
  float pushsum = 0.f;
  if (t == 0) { for (int i = 0; i < 8; ++i) pushsum += red[i]; }
  __syncthreads();

  v = regacc;
  #pragma unroll
  for (int off = 32; off; off >>= 1) v += __shfl_down(v, off, 64);
  if ((t & 63) == 0) red[t >> 6] = v;
  __syncthreads();

  if (t == 0) {
    float regsum = 0.f;
    for (int i = 0; i < 8; ++i) regsum += red[i];
    float nv = 0.f;
    for (int i = 0; i < KC; ++i) nv += validf[i];
    const float ncomp = nv * (nv - 1.f) * 0.5f;
    const float push  = (nv >= 2.f) ? pushsum / fmaxf(ncomp, 1.f) : 0.f;
    const float reg   = regsum / fmaxf(nv * (float)CH, 1.f);
    ws[WS_PR + b] = push + 1e-4f * reg;
  }
}

__global__ __launch_bounds__(256) void pull_kernel(
    const float4* __restrict__ embv, const int* __restrict__ lab,
    float* __restrict__ ws) {
  __shared__ float cent[CH * KC];   // [c][k]: read bank == label -> broadcast/spread
  __shared__ float red[4];
  const int t = threadIdx.x;
  const int b = blockIdx.x / PBPI, blk = blockIdx.x % PBPI;
  for (int i = t; i < CH * KC; i += 256)
    cent[i] = ws[WS_CEN + (size_t)b * CH * KC + i];
  __syncthreads();

  float acc = 0.f;
  const size_t pix0 = (size_t)b * NPI + (size_t)blk * PPPB;
  for (int it = 0; it < PIT; ++it) {
    const size_t p = pix0 + (size_t)it * 256 + t;
    const int L = lab[p];
    const float4 v0 = embv[p * 4 + 0];
    const float4 v1 = embv[p * 4 + 1];
    const float4 v2 = embv[p * 4 + 2];
    const float4 v3 = embv[p * 4 + 3];
    float d = 0.f;
    d += fabsf(v0.x - cent[ 0 * KC + L]);
    d += fabsf(v0.y - cent[ 1 * KC + L]);
    d += fabsf(v0.z - cent[ 2 * KC + L]);
    d += fabsf(v0.w - cent[ 3 * KC + L]);
    d += fabsf(v1.x - cent[ 4 * KC + L]);
    d += fabsf(v1.y - cent[ 5 * KC + L]);
    d += fabsf(v1.z - cent[ 6 * KC + L]);
    d += fabsf(v1.w - cent[ 7 * KC + L]);
    d += fabsf(v2.x - cent[ 8 * KC + L]);
    d += fabsf(v2.y - cent[ 9 * KC + L]);
    d += fabsf(v2.z - cent[10 * KC + L]);
    d += fabsf(v2.w - cent[11 * KC + L]);
    d += fabsf(v3.x - cent[12 * KC + L]);
    d += fabsf(v3.y - cent[13 * KC + L]);
    d += fabsf(v3.z - cent[14 * KC + L]);
    d += fabsf(v3.w - cent[15 * KC + L]);
    acc += d * d;
  }
  #pragma unroll
  for (int off = 32; off; off >>= 1) acc += __shfl_down(acc, off, 64);
  if ((t & 63) == 0) red[t >> 6] = acc;
  __syncthreads();
  if (t == 0) ws[WS_PLP + blockIdx.x] = red[0] + red[1] + red[2] + red[3];
}

__global__ void final_kernel(const float* __restrict__ ws, float* __restrict__ out) {
  __shared__ float simg[NB];
  const int t = threadIdx.x;            // 256 threads
  const int img = t >> 5, j = t & 31;   // 32 threads per image
  float v = 0.f;
  #pragma unroll
  for (int q = 0; q < PBPI / 32; ++q)
    v += ws[WS_PLP + img * PBPI + j + 32 * q];
  #pragma unroll
  for (int off = 16; off; off >>= 1) v += __shfl_down(v, off, 32);
  if (j == 0) simg[img] = v;
  __syncthreads();
  if (t == 0) {
    float s = 0.f;
    for (int b2 = 0; b2 < NB; ++b2)
      s += ws[WS_PR + b2] + simg[b2] * (1.f / (float)NPI);
    out[0] = s * (1.f / (float)NB);
  }
}

extern "C" void kernel_launch(void* const* d_in, const int* in_sizes, int n_in,
                              void* d_out, int out_size, void* d_ws, size_t ws_size,
                              hipStream_t stream) {
  const float4* emb = (const float4*)d_in[0];
  const int*    lab = (const int*)d_in[1];
  float* ws  = (float*)d_ws;
  float* out = (float*)d_out;

  hipLaunchKernelGGL(segsum_kernel, dim3(NB * SBPI), dim3(256), 0, stream, emb, lab, ws);
  hipLaunchKernelGGL(centroid_push_kernel, dim3(NB), dim3(512), 0, stream, ws);
  hipLaunchKernelGGL(pull_kernel, dim3(NB * PBPI), dim3(256), 0, stream, emb, lab, ws);
  hipLaunchKernelGGL(final_kernel, dim3(1), dim3(256), 0, stream, ws, out);
}

// Round 9
// 58.266 us; speedup vs baseline: 7.0712x; 1.5982x over previous
//
#include <hip/hip_runtime.h>

#define KC 32
#define CH 16
#define NB 8
#define NPI (512*512)

// segsum decomposition: 2048 blocks of 256 threads (8 blocks/CU)
#define SBPI 256              // blocks per image
#define SPPB (NPI/SBPI)       // 1024 px per block
#define SPW  (SPPB/4)         // 256 px per wave
#define SCH  (SPW/64)         // 4 chunks of 64 px

// pull decomposition: 2048 blocks of 256 threads
#define PBPI 256
#define PPPB (NPI/PBPI)       // 1024
#define PIT  (PPPB/256)       // 4

// ws layout (floats); every cell written before read each call -> no pre-zero
#define WS_PART 0                          // [2048][544] per-block segsum partials ([k][c|cnt])
#define WS_SUMS (WS_PART + NB*SBPI*544)    // [8][544] per-image reduced sums
#define WS_CEN (WS_SUMS + NB*544)          // [8][16][32] centroids [c][k]
#define WS_PR  (WS_CEN + NB*CH*KC)         // [8] push + 1e-4*reg
#define WS_PLP (WS_PR + NB)                // [2048] pull partials

typedef float f32x16 __attribute__((ext_vector_type(16)));
typedef short short8 __attribute__((ext_vector_type(8)));

__device__ __forceinline__ unsigned short f2bf(float x) {
  unsigned u = __builtin_bit_cast(unsigned, x);
  u += 0x7FFFu + ((u >> 16) & 1u);          // RNE to bf16
  return (unsigned short)(u >> 16);
}
__device__ __forceinline__ unsigned packbf(float lo, float hi) {
  return (unsigned)f2bf(lo) | ((unsigned)f2bf(hi) << 16);
}

// sums[k][c] + counts[k] via onehot^T * emb, one 32x32x16 bf16 MFMA per 16 pixels.
// Per-wave private LDS staging (in-order DS per wave => no barriers in hot loop).
// Block partials stored with PLAIN stores (no atomics anywhere).
__global__ __launch_bounds__(256) void segsum_kernel(
    const float4* __restrict__ embv, const int* __restrict__ lab,
    float* __restrict__ ws) {
  __shared__ unsigned smem[4][8][68];   // [wave][ch-pair][px + pad] bf16x2
  __shared__ int      slab[4][64];
  __shared__ float    sred[4][KC * 17];

  const int t = threadIdx.x, w = t >> 6, l = t & 63;
  const int b = blockIdx.x / SBPI, blk = blockIdx.x % SBPI;
  const size_t base = (size_t)b * NPI + (size_t)blk * SPPB + (size_t)w * SPW;
  const int h = l >> 5;     // k-half of the MFMA operands
  const int m = l & 31;     // A row (label) / B col (channel|count)

  f32x16 acc;
  #pragma unroll
  for (int i = 0; i < 16; ++i) acc[i] = 0.f;

  float4 c0, c1, c2, c3; int cl;
  {
    const float4* ep = embv + (base + l) * 4;
    c0 = ep[0]; c1 = ep[1]; c2 = ep[2]; c3 = ep[3];
    cl = lab[base + l];
  }

  for (int ch = 0; ch < SCH; ++ch) {
    smem[w][0][l] = packbf(c0.x, c0.y);
    smem[w][1][l] = packbf(c0.z, c0.w);
    smem[w][2][l] = packbf(c1.x, c1.y);
    smem[w][3][l] = packbf(c1.z, c1.w);
    smem[w][4][l] = packbf(c2.x, c2.y);
    smem[w][5][l] = packbf(c2.z, c2.w);
    smem[w][6][l] = packbf(c3.x, c3.y);
    smem[w][7][l] = packbf(c3.z, c3.w);
    slab[w][l] = cl;

    if (ch + 1 < SCH) {                 // prefetch next chunk under the MFMA steps
      const size_t p = base + (size_t)(ch + 1) * 64 + l;
      const float4* ep = embv + p * 4;
      c0 = ep[0]; c1 = ep[1]; c2 = ep[2]; c3 = ep[3];
      cl = lab[p];
    }

    #pragma unroll
    for (int s = 0; s < 4; ++s) {
      const int4* lp = (const int4*)&slab[w][s * 16 + 8 * h];
      const int4 la = lp[0], lb = lp[1];
      const short ONE = (short)0x3F80;  // bf16 1.0
      short8 av;
      av[0] = (la.x == m) ? ONE : (short)0; av[1] = (la.y == m) ? ONE : (short)0;
      av[2] = (la.z == m) ? ONE : (short)0; av[3] = (la.w == m) ? ONE : (short)0;
      av[4] = (lb.x == m) ? ONE : (short)0; av[5] = (lb.y == m) ? ONE : (short)0;
      av[6] = (lb.z == m) ? ONE : (short)0; av[7] = (lb.w == m) ? ONE : (short)0;

      short8 bv;
      if (m < CH) {
        const uint4* fp = (const uint4*)&smem[w][m >> 1][s * 16 + 8 * h];
        const uint4 u0 = fp[0], u1 = fp[1];
        const unsigned sh = (unsigned)(m & 1) * 16u;
        bv[0] = (short)((u0.x >> sh) & 0xFFFFu); bv[1] = (short)((u0.y >> sh) & 0xFFFFu);
        bv[2] = (short)((u0.z >> sh) & 0xFFFFu); bv[3] = (short)((u0.w >> sh) & 0xFFFFu);
        bv[4] = (short)((u1.x >> sh) & 0xFFFFu); bv[5] = (short)((u1.y >> sh) & 0xFFFFu);
        bv[6] = (short)((u1.z >> sh) & 0xFFFFu); bv[7] = (short)((u1.w >> sh) & 0xFFFFu);
      } else {
        const short cv = (m == CH) ? ONE : (short)0;   // col 16 = ones -> counts
        #pragma unroll
        for (int e = 0; e < 8; ++e) bv[e] = cv;
      }
      acc = __builtin_amdgcn_mfma_f32_32x32x16_bf16(av, bv, acc, 0, 0, 0);
    }
  }

  // block-level reduce of the 4 waves' [32 x 17] partials, plain store of partials
  if (m < 17) {
    #pragma unroll
    for (int r = 0; r < 16; ++r) {
      const int row = (r & 3) + 8 * (r >> 2) + 4 * h;   // verified C/D layout (m74/m101)
      sred[w][row * 17 + m] = acc[r];
    }
  }
  __syncthreads();
  for (int i = t; i < KC * 17; i += 256) {
    const float v = sred[0][i] + sred[1][i] + sred[2][i] + sred[3][i];
    ws[WS_PART + (size_t)blockIdx.x * 544 + i] = v;
  }
}

// Parallel partial-reduce: 136 blocks = 8 images x 17 cell-chunks of 32.
// Thread (pslice = t/32, cidx = t%32) sums 32 of the 256 partials, coalesced;
// every 64B line of the 4.5 MB partial array is read exactly once, grid-wide.
__global__ __launch_bounds__(256) void mid_reduce_kernel(float* __restrict__ ws) {
  __shared__ float part[8][33];     // [pslice][cell], padded
  const int g = blockIdx.x, t = threadIdx.x;
  const int img = g / 17, c0 = (g % 17) * 32;
  const int cidx = t & 31, ps = t >> 5;

  const float* base = ws + WS_PART + (size_t)(img * SBPI) * 544 + c0 + cidx;
  float s = 0.f;
  #pragma unroll 8
  for (int q = 0; q < SBPI / 8; ++q)
    s += base[(size_t)(ps + 8 * q) * 544];
  part[ps][cidx] = s;
  __syncthreads();
  if (t < 32) {
    float v = 0.f;
    #pragma unroll
    for (int i = 0; i < 8; ++i) v += part[i][t];
    ws[WS_SUMS + img * 544 + c0 + t] = v;
  }
}

// Centroids + push + reg from the reduced sums. One block per image.
__global__ __launch_bounds__(512) void centroid_push_kernel(float* __restrict__ ws) {
  __shared__ float sums_s[KC * 17];  // [k][c|cnt]
  __shared__ float cent[CH * KC];    // [c][k]
  __shared__ float validf[KC];
  __shared__ float red[8];
  const int b = blockIdx.x, t = threadIdx.x;

  for (int i = t; i < KC * 17; i += 512) sums_s[i] = ws[WS_SUMS + b * 544 + i];
  __syncthreads();

  if (t < KC) validf[t] = (sums_s[t * 17 + 16] > 0.f) ? 1.f : 0.f;

  const int k = t & 31, c = t >> 5;   // t in [0,512) covers all (k,c)
  const float cnt = sums_s[k * 17 + 16];
  const float ce  = (cnt > 0.f) ? sums_s[k * 17 + c] / cnt : 0.f;
  cent[c * KC + k] = ce;
  ws[WS_CEN + (size_t)b * CH * KC + c * KC + k] = ce;
  const float regacc = ce * ce;
  __syncthreads();

  float pushacc = 0.f;
  for (int p = t; p < KC * KC; p += 512) {
    const int i = p >> 5, j = p & 31;
    if (i < j && validf[i] > 0.f && validf[j] > 0.f) {
      float pd = 0.f;
      #pragma unroll
      for (int cc = 0; cc < CH; ++cc)
        pd += fabsf(cent[cc * KC + i] - cent[cc * KC + j]);
      const float hi = 0.25f - pd;
      if (hi > 0.f) pushacc += hi * hi;
    }
  }

  float v = pushacc;
  #pragma unroll
  for (int off = 32; off; off >>= 1) v += __shfl_down(v, off, 64);
  if ((t & 63) == 0) red[t >> 6] = v;
  __syncthreads();
  float pushsum = 0.f;
  if (t == 0) { for (int i = 0; i < 8; ++i) pushsum += red[i]; }
  __syncthreads();

  v = regacc;
  #pragma unroll
  for (int off = 32; off; off >>= 1) v += __shfl_down(v, off, 64);
  if ((t & 63) == 0) red[t >> 6] = v;
  __syncthreads();

  if (t == 0) {
    float regsum = 0.f;
    for (int i = 0; i < 8; ++i) regsum += red[i];
    float nv = 0.f;
    for (int i = 0; i < KC; ++i) nv += validf[i];
    const float ncomp = nv * (nv - 1.f) * 0.5f;
    const float push  = (nv >= 2.f) ? pushsum / fmaxf(ncomp, 1.f) : 0.f;
    const float reg   = regsum / fmaxf(nv * (float)CH, 1.f);
    ws[WS_PR + b] = push + 1e-4f * reg;
  }
}

__global__ __launch_bounds__(256) void pull_kernel(
    const float4* __restrict__ embv, const int* __restrict__ lab,
    float* __restrict__ ws) {
  __shared__ float cent[CH * KC];   // [c][k]: read bank == label -> broadcast/spread
  __shared__ float red[4];
  const int t = threadIdx.x;
  const int b = blockIdx.x / PBPI, blk = blockIdx.x % PBPI;
  for (int i = t; i < CH * KC; i += 256)
    cent[i] = ws[WS_CEN + (size_t)b * CH * KC + i];
  __syncthreads();

  float acc = 0.f;
  const size_t pix0 = (size_t)b * NPI + (size_t)blk * PPPB;
  for (int it = 0; it < PIT; ++it) {
    const size_t p = pix0 + (size_t)it * 256 + t;
    const int L = lab[p];
    const float4 v0 = embv[p * 4 + 0];
    const float4 v1 = embv[p * 4 + 1];
    const float4 v2 = embv[p * 4 + 2];
    const float4 v3 = embv[p * 4 + 3];
    float d = 0.f;
    d += fabsf(v0.x - cent[ 0 * KC + L]);
    d += fabsf(v0.y - cent[ 1 * KC + L]);
    d += fabsf(v0.z - cent[ 2 * KC + L]);
    d += fabsf(v0.w - cent[ 3 * KC + L]);
    d += fabsf(v1.x - cent[ 4 * KC + L]);
    d += fabsf(v1.y - cent[ 5 * KC + L]);
    d += fabsf(v1.z - cent[ 6 * KC + L]);
    d += fabsf(v1.w - cent[ 7 * KC + L]);
    d += fabsf(v2.x - cent[ 8 * KC + L]);
    d += fabsf(v2.y - cent[ 9 * KC + L]);
    d += fabsf(v2.z - cent[10 * KC + L]);
    d += fabsf(v2.w - cent[11 * KC + L]);
    d += fabsf(v3.x - cent[12 * KC + L]);
    d += fabsf(v3.y - cent[13 * KC + L]);
    d += fabsf(v3.z - cent[14 * KC + L]);
    d += fabsf(v3.w - cent[15 * KC + L]);
    acc += d * d;
  }
  #pragma unroll
  for (int off = 32; off; off >>= 1) acc += __shfl_down(acc, off, 64);
  if ((t & 63) == 0) red[t >> 6] = acc;
  __syncthreads();
  if (t == 0) ws[WS_PLP + blockIdx.x] = red[0] + red[1] + red[2] + red[3];
}

__global__ void final_kernel(const float* __restrict__ ws, float* __restrict__ out) {
  __shared__ float simg[NB];
  const int t = threadIdx.x;            // 256 threads
  const int img = t >> 5, j = t & 31;   // 32 threads per image
  float v = 0.f;
  #pragma unroll
  for (int q = 0; q < PBPI / 32; ++q)
    v += ws[WS_PLP + img * PBPI + j + 32 * q];
  #pragma unroll
  for (int off = 16; off; off >>= 1) v += __shfl_down(v, off, 32);
  if (j == 0) simg[img] = v;
  __syncthreads();
  if (t == 0) {
    float s = 0.f;
    for (int b2 = 0; b2 < NB; ++b2)
      s += ws[WS_PR + b2] + simg[b2] * (1.f / (float)NPI);
    out[0] = s * (1.f / (float)NB);
  }
}

extern "C" void kernel_launch(void* const* d_in, const int* in_sizes, int n_in,
                              void* d_out, int out_size, void* d_ws, size_t ws_size,
                              hipStream_t stream) {
  const float4* emb = (const float4*)d_in[0];
  const int*    lab = (const int*)d_in[1];
  float* ws  = (float*)d_ws;
  float* out = (float*)d_out;

  hipLaunchKernelGGL(segsum_kernel, dim3(NB * SBPI), dim3(256), 0, stream, emb, lab, ws);
  hipLaunchKernelGGL(mid_reduce_kernel, dim3(NB * 17), dim3(256), 0, stream, ws);
  hipLaunchKernelGGL(centroid_push_kernel, dim3(NB), dim3(512), 0, stream, ws);
  hipLaunchKernelGGL(pull_kernel, dim3(NB * PBPI), dim3(256), 0, stream, emb, lab, ws);
  hipLaunchKernelGGL(final_kernel, dim3(1), dim3(256), 0, stream, ws, out);
}